// Round 7
// baseline (375.381 us; speedup 1.0000x reference)
//
#include <hip/hip_runtime.h>
#include <cstdint>
#include <cstddef>

#define M_DIM 4096
#define K_DIM 4096
#define N_DIM 11008
#define BM 256
#define BN 256
#define BKB 128                       /* K bytes per K-tile = 4 slices of K=32 */
#define NT (K_DIM / BKB)              /* 32 K-tiles */
#define NTM (M_DIM / BM)              /* 16 */
#define NTN (N_DIM / BN)              /* 43 */
#define SLOT_BYTES 65536              /* A 32KB + B 32KB */
#define B_OFF 32768

typedef int   int4v   __attribute__((ext_vector_type(4)));
typedef int   int16v  __attribute__((ext_vector_type(16)));
typedef float float4v __attribute__((ext_vector_type(4)));

__device__ __forceinline__ void gload_lds16(const void* g, void* l) {
  __builtin_amdgcn_global_load_lds(
      (const __attribute__((address_space(1))) unsigned int*)g,
      (__attribute__((address_space(3))) unsigned int*)l, 16, 0, 0);
}

// ---------------- x quantization: fp32 -> int8 ----------------
__global__ void quant_x_kernel(const float* __restrict__ x,
                               const float* __restrict__ scale_p,
                               const int* __restrict__ off_p,
                               signed char* __restrict__ xq, int total16) {
  const float inv = 1.0f / scale_p[0];
  const float off = (float)off_p[0];
  int tid = blockIdx.x * blockDim.x + threadIdx.x;
  int stride = gridDim.x * blockDim.x;
  const float4v* x4 = (const float4v*)x;
  int4v* out4 = (int4v*)xq;
  for (int i = tid; i < total16; i += stride) {
    int4v o;
#pragma unroll
    for (int j = 0; j < 4; ++j) {
      float4v v = x4[(size_t)i * 4 + j];
      int r = 0;
#pragma unroll
      for (int e = 0; e < 4; ++e) {
        float q = rintf(v[e] * inv) + off;     // round-half-even, matches jnp.round
        q = fminf(fmaxf(q, -128.0f), 127.0f);
        int qi = (int)q;
        r |= (qi & 0xff) << (8 * e);
      }
      o[j] = r;
    }
    out4[i] = o;
  }
}

// ---------------- weight pack: int32 carrier -> int8 ----------------
__global__ void pack_w_kernel(const int* __restrict__ w,
                              signed char* __restrict__ wq, int total16) {
  int tid = blockIdx.x * blockDim.x + threadIdx.x;
  int stride = gridDim.x * blockDim.x;
  const int4v* w4 = (const int4v*)w;
  int4v* out4 = (int4v*)wq;
  for (int i = tid; i < total16; i += stride) {
    int4v o;
#pragma unroll
    for (int j = 0; j < 4; ++j) {
      int4v v = w4[(size_t)i * 4 + j];
      o[j] = (v[0] & 0xff) | ((v[1] & 0xff) << 8) |
             ((v[2] & 0xff) << 16) | ((v[3] & 0xff) << 24);
    }
    out4[i] = o;
  }
}

// ------ int8 GEMM: 256x256, 8 waves, mfma_i32_32x32x32_i8, 2 fat phases/tile -----
// A: xq [M][K] int8, B: wq [N][K] int8 (B^T), out fp32 [M][N]
// LDS fragment-packed, 32-row frags: frag(a,ks) = 1 KB holding rows a*32..+31,
// K bytes ks*32..+31; lane l's 16B at frag*1024 + l*16 = [a*32+(l&31)][ks*32+
// (l>>5)*16 ..+16].  A frags at (a*4+ks)*1024, B at B_OFF + same.  2 slots.
// Per tile: P0 {stage kt+1 (8 gloads); read H1=ks23 (12 ds); lgkm(12); 16 MFMA;
// vmcnt(0); barrier}  P1 {read kt+1 H0=ks01 from nxt; lgkm(12); 16 MFMA; barrier}
// All lgkm waits are no-ops in steady state (reads issued a full phase ahead).
__global__ __launch_bounds__(512, 2) void gemm_i8_kernel(
    const signed char* __restrict__ A,
    const signed char* __restrict__ B,
    const int* __restrict__ qbias,
    const float* __restrict__ dscale,
    float* __restrict__ out) {
  __shared__ __attribute__((aligned(16))) signed char lds[2 * SLOT_BYTES];  // 128 KB

  const int tid  = threadIdx.x;
  const int lane = tid & 63;
  const int wv   = tid >> 6;   // 0..7
  const int wr   = wv >> 2;    // 0..1  (M half: 128 rows = 4 x 32)
  const int wc   = wv & 3;     // 0..3  (N quarter: 64 cols = 2 x 32)

  // XCD swizzle (R6-style, FETCH 200 MB): xcd owns tm {2x,2x+1}; pairs share B.
  int bid = blockIdx.x;
  int s   = bid >> 3;                 // 0..85
  int tm  = 2 * (bid & 7) + (s & 1);  // 0..15
  int tn  = s >> 1;                   // 0..42

  // ---- staging: wave wv stages A frag a=wv (ks=0..3) and B frag b=wv ----
  const signed char* pA = A + (size_t)(tm * BM + wv * 32 + (lane & 31)) * K_DIM
                            + (lane >> 5) * 16;
  const signed char* pB = B + (size_t)(tn * BN + wv * 32 + (lane & 31)) * K_DIM
                            + (lane >> 5) * 16;

#define STG(KTW, SO) do {                                                     \
    _Pragma("unroll") for (int ks = 0; ks < 4; ++ks) {                        \
      gload_lds16(pA + (size_t)(KTW) * BKB + ks * 32,                         \
                  lds + (SO) + ((wv * 4 + ks) << 10));                        \
      gload_lds16(pB + (size_t)(KTW) * BKB + ks * 32,                         \
                  lds + (SO) + B_OFF + ((wv * 4 + ks) << 10));                \
    } } while (0)

  // ---- ds_read: A frags a = wr*4+m, B frags b = wc*2+nn (conflict-free) ----
#define RD_HALF(AH, BH, SO, KB) do {                                          \
    _Pragma("unroll") for (int m = 0; m < 4; ++m)                             \
      _Pragma("unroll") for (int kk = 0; kk < 2; ++kk)                        \
        AH[m][kk] = *(const int4v*)(lds + (SO) +                              \
            (((wr * 4 + m) * 4 + (KB) + kk) << 10) + lane * 16);              \
    _Pragma("unroll") for (int nn = 0; nn < 2; ++nn)                          \
      _Pragma("unroll") for (int kk = 0; kk < 2; ++kk)                        \
        BH[nn][kk] = *(const int4v*)(lds + (SO) + B_OFF +                     \
            (((wc * 2 + nn) * 4 + (KB) + kk) << 10) + lane * 16);             \
  } while (0)

#define MFMA_HALF(AH, BH) do {                                                \
    __builtin_amdgcn_s_setprio(1);                                            \
    _Pragma("unroll") for (int m = 0; m < 4; ++m)                             \
      _Pragma("unroll") for (int nn = 0; nn < 2; ++nn)                        \
        _Pragma("unroll") for (int kk = 0; kk < 2; ++kk)                      \
          acc[m][nn] = __builtin_amdgcn_mfma_i32_32x32x32_i8(                 \
              AH[m][kk], BH[nn][kk], acc[m][nn], 0, 0, 0);                    \
    __builtin_amdgcn_s_setprio(0);                                            \
  } while (0)

  int16v acc[4][2];
#pragma unroll
  for (int i = 0; i < 4; ++i)
#pragma unroll
    for (int j = 0; j < 2; ++j)
#pragma unroll
      for (int e = 0; e < 16; ++e) acc[i][j][e] = 0;

  int4v AH0[4][2], AH1[4][2], BH0[2][2], BH1[2][2];

  // ---- prologue: stage tiles 0,1; read tile0 H0 ----
  STG(0, 0);
  STG(1, SLOT_BYTES);
  asm volatile("s_waitcnt vmcnt(8)" ::: "memory");   // tile 0 landed
  __builtin_amdgcn_s_barrier();
  __builtin_amdgcn_sched_barrier(0);
  RD_HALF(AH0, BH0, 0, 0);                           // 12 lgkm outstanding

#define TILE(KT, S) do {                                                      \
    const int cur_ = (S) * SLOT_BYTES;                                        \
    const int nxt_ = cur_ ^ SLOT_BYTES;                                       \
    /* P0: stage kt+1 -> nxt, read H1(cur), MFMA H0 */                        \
    STG(((KT) + 1) & (NT - 1), nxt_);                                         \
    RD_HALF(AH1, BH1, cur_, 2);                                               \
    asm volatile("s_waitcnt lgkmcnt(12)" ::: "memory");  /* H0 done */        \
    __builtin_amdgcn_sched_barrier(0);                                        \
    MFMA_HALF(AH0, BH0);                                                      \
    asm volatile("s_waitcnt vmcnt(0)" ::: "memory");     /* kt+1 landed */    \
    __builtin_amdgcn_s_barrier();                        /* kt+1 visible */   \
    /* P1: read kt+1 H0 from nxt, MFMA H1 */                                  \
    RD_HALF(AH0, BH0, nxt_, 0);                                               \
    asm volatile("s_waitcnt lgkmcnt(12)" ::: "memory");  /* H1 done */        \
    __builtin_amdgcn_sched_barrier(0);                                        \
    MFMA_HALF(AH1, BH1);                                                      \
    __builtin_amdgcn_s_barrier();   /* all cur reads drained; safe to ovw */  \
  } while (0)

  for (int t = 0; t < NT / 2; ++t) {
    TILE(2 * t,     0);
    TILE(2 * t + 1, 1);
  }
  asm volatile("s_waitcnt vmcnt(0) lgkmcnt(0)" ::: "memory");  // drain tail
#undef TILE
#undef MFMA_HALF
#undef RD_HALF
#undef STG

  // ---- epilogue: out[m][n] = (acc + qbias[n]) * dscale[n] ----
  // 32x32 C/D: col = lane&31, row = (reg&3) + 8*(reg>>2) + 4*(lane>>5)
  const int col = lane & 31;
  const int rb  = (lane >> 5) * 4;
  const int gm0 = tm * BM + wr * 128;
  const int gn0 = tn * BN + wc * 64;
#pragma unroll
  for (int nn = 0; nn < 2; ++nn) {
    int gn = gn0 + nn * 32 + col;
    float ds = dscale[gn];
    int qb = qbias[gn];
#pragma unroll
    for (int m = 0; m < 4; ++m) {
      int gm = gm0 + m * 32 + rb;
#pragma unroll
      for (int r = 0; r < 16; ++r) {
        int row = gm + (r & 3) + 8 * (r >> 2);
        out[(size_t)row * N_DIM + gn] = (float)(acc[m][nn][r] + qb) * ds;
      }
    }
  }
}

extern "C" void kernel_launch(void* const* d_in, const int* in_sizes, int n_in,
                              void* d_out, int out_size, void* d_ws, size_t ws_size,
                              hipStream_t stream) {
  const float* x      = (const float*)d_in[0];
  const int*   w      = (const int*)d_in[1];
  const float* dscale = (const float*)d_in[2];
  const float* iscale = (const float*)d_in[3];
  const int*   ioff   = (const int*)d_in[4];
  const int*   qbias  = (const int*)d_in[5];
  float* out = (float*)d_out;

  const size_t xq_bytes = (size_t)M_DIM * K_DIM;        // 16 MB
  const size_t wq_bytes = (size_t)N_DIM * K_DIM;        // 45 MB
  if (ws_size < xq_bytes + wq_bytes) return;

  signed char* xq = (signed char*)d_ws;
  signed char* wq = (signed char*)d_ws + xq_bytes;

  quant_x_kernel<<<2048, 256, 0, stream>>>(x, iscale, ioff, xq, M_DIM * K_DIM / 16);
  pack_w_kernel<<<2048, 256, 0, stream>>>(w, wq, N_DIM * K_DIM / 16);
  gemm_i8_kernel<<<NTM * NTN, 512, 0, stream>>>(xq, wq, qbias, dscale, out);
}